// Round 3
// baseline (1183.610 us; speedup 1.0000x reference)
//
#include <hip/hip_runtime.h>
#include <hip/hip_fp16.h>
#include <math.h>

// Problem constants
#define NB 16     // batch
#define SQ 40     // seq len
#define HIDN 256  // hidden = E = R
#define CC 1024   // C
#define NROW 262144 // R*C

__device__ __forceinline__ float sigf(float x){ return 1.0f/(1.0f+__expf(-x)); }

typedef _Float16 h2v __attribute__((ext_vector_type(2)));
typedef _Float16 f16x8 __attribute__((ext_vector_type(8)));
typedef float    f32x4 __attribute__((ext_vector_type(4)));

__device__ __forceinline__ float fd2(unsigned w, unsigned h, float acc){
  h2v a = __builtin_bit_cast(h2v, w);
  h2v b = __builtin_bit_cast(h2v, h);
#if __has_builtin(__builtin_amdgcn_fdot2)
  return __builtin_amdgcn_fdot2(a, b, acc, false);
#else
  return acc + (float)a.x*(float)b.x + (float)a.y*(float)b.y;
#endif
}

__device__ __forceinline__ unsigned pkh(float lo, float hi){
  return (unsigned)__half_as_ushort(__float2half_rn(lo))
       | ((unsigned)__half_as_ushort(__float2half_rn(hi)) << 16);
}

// ---------------- K0: x-gates precompute: XG[t*16+b][row] = emb[idx[b][t]] . w_ih[row] + b_ih + b_hh
__global__ __launch_bounds__(256) void k_xgates(
    const int* __restrict__ idx, const float* __restrict__ emb,
    const float* __restrict__ w_ih, const float* __restrict__ b_ih,
    const float* __restrict__ b_hh, float* __restrict__ XG)
{
  __shared__ float xs[8*256];
  int t = threadIdx.x;
  int tb0 = blockIdx.x * 8;
  #pragma unroll
  for (int i = 0; i < 8; ++i) {
    int flat = t + i*256;
    int p = flat >> 8, k = flat & 255;
    int tb = tb0 + p;
    int ts = tb >> 4, b = tb & 15;
    int row = idx[b*SQ + ts];
    xs[p*256 + k] = emb[row*256 + k];
  }
  __syncthreads();
  int rows[4];
  float acc[4][8];
  #pragma unroll
  for (int r = 0; r < 4; ++r) {
    rows[r] = t + r*256;
    float bias = b_ih[rows[r]] + b_hh[rows[r]];
    #pragma unroll
    for (int p = 0; p < 8; ++p) acc[r][p] = bias;
  }
  for (int k16 = 0; k16 < 16; ++k16) {
    float4 w[4][4];
    #pragma unroll
    for (int r = 0; r < 4; ++r)
      #pragma unroll
      for (int q = 0; q < 4; ++q)
        w[r][q] = *(const float4*)&w_ih[rows[r]*256 + k16*16 + q*4];
    #pragma unroll
    for (int p = 0; p < 8; ++p) {
      #pragma unroll
      for (int q = 0; q < 4; ++q) {
        float4 x = *(const float4*)&xs[p*256 + k16*16 + q*4];
        #pragma unroll
        for (int r = 0; r < 4; ++r)
          acc[r][p] += w[r][q].x*x.x + w[r][q].y*x.y + w[r][q].z*x.z + w[r][q].w*x.w;
      }
    }
  }
  #pragma unroll
  for (int p = 0; p < 8; ++p)
    #pragma unroll
    for (int r = 0; r < 4; ++r)
      XG[(tb0 + p)*1024 + rows[r]] = acc[r][p];
}

// ---------------- K-whh4: pack w_hh fp32 -> f16-pair uint4, layout for k_lstm1b coalesced reg load.
// W4u4[q4*1024 + row] = pairs {8q4..8q4+7} of w_hh[row][:]. q4 in [0,32), row in [0,1024).
__global__ __launch_bounds__(256) void k_whh4(const float* __restrict__ w, uint4* __restrict__ W4)
{
  int tid = blockIdx.x*256 + threadIdx.x;   // 32768 total
  int row = tid >> 5;
  int q4  = tid & 31;
  const float* src = &w[(size_t)row*256 + q4*8];
  float4 a = *(const float4*)src;
  float4 b = *(const float4*)(src + 4);
  uint4 o;
  o.x = pkh(a.x, a.y);
  o.y = pkh(a.z, a.w);
  o.z = pkh(b.x, b.y);
  o.w = pkh(b.z, b.w);
  W4[(size_t)q4*1024 + row] = o;
}

// ---------------- K1: LSTM, ONE block per batch (grid 16 x 1024 thr). Zero cross-block sync.
// Thread t owns gate row t (i:0-255, f:256-511, g:512-767, o:768-1023); its 256 w_hh
// weights are register-resident (128 packed-f16 u32). h is block-local: packed pairs in LDS,
// each wave pulls 128 pairs into 2 regs and broadcasts via readlane into fdot2.
__global__ __launch_bounds__(1024) void k_lstm1b(
    const float* __restrict__ XG, const uint4* __restrict__ W4,
    const int* __restrict__ lens, const float* __restrict__ e2d_w,
    const float* __restrict__ e2d_b, float* __restrict__ instr)
{
  __shared__ float dot_s[1024];
  __shared__ float h_s[256];
  __shared__ unsigned h_pk[128];

  int t = threadIdx.x;
  int b = blockIdx.x;
  int len = lens[b];
  int lane = t & 63;

  // coalesced register weight load: 32 x uint4 -> 128 packed pairs
  unsigned wv[128];
  #pragma unroll
  for (int q4 = 0; q4 < 32; ++q4) {
    uint4 v = W4[(size_t)q4*1024 + t];
    wv[4*q4+0]=v.x; wv[4*q4+1]=v.y; wv[4*q4+2]=v.z; wv[4*q4+3]=v.w;
  }

  // per-thread state: t<128 owns units 2t, 2t+1
  float c0 = 0.0f, c1 = 0.0f, h0r = 0.0f, h1r = 0.0f;

  float xg_cur = XG[(0*NB + b)*1024 + t];

  for (int it = 0; it < SQ; ++it) {
    float xg_next = (it+1 < SQ) ? XG[((it+1)*NB + b)*1024 + t] : 0.0f;
    float acc = xg_cur;
    if (it > 0) {
      int hp0 = (int)h_pk[lane];
      int hp1 = (int)h_pk[64 + lane];
      float a0 = acc, a1 = 0.0f;
      #pragma unroll
      for (int q = 0; q < 64; q += 2) {
        a0 = fd2(wv[q],   (unsigned)__builtin_amdgcn_readlane(hp0, q),   a0);
        a1 = fd2(wv[q+1], (unsigned)__builtin_amdgcn_readlane(hp0, q+1), a1);
      }
      #pragma unroll
      for (int q = 0; q < 64; q += 2) {
        a0 = fd2(wv[64+q],   (unsigned)__builtin_amdgcn_readlane(hp1, q),   a0);
        a1 = fd2(wv[64+q+1], (unsigned)__builtin_amdgcn_readlane(hp1, q+1), a1);
      }
      acc = a0 + a1;
    }
    dot_s[t] = acc;
    __syncthreads();
    if (t < 128) {
      float2 di = *(const float2*)&dot_s[2*t];
      float2 df = *(const float2*)&dot_s[2*t + 256];
      float2 dg = *(const float2*)&dot_s[2*t + 512];
      float2 dv = *(const float2*)&dot_s[2*t + 768];
      float cn0 = sigf(df.x)*c0 + sigf(di.x)*tanhf(dg.x);
      float hn0 = sigf(dv.x)*tanhf(cn0);
      float cn1 = sigf(df.y)*c1 + sigf(di.y)*tanhf(dg.y);
      float hn1 = sigf(dv.y)*tanhf(cn1);
      if (it < len) { c0 = cn0; h0r = hn0; c1 = cn1; h1r = hn1; }
      h_pk[t] = pkh(h0r, h1r);
      h_s[2*t] = h0r; h_s[2*t + 1] = h1r;
    }
    __syncthreads();
    xg_cur = xg_next;
  }

  // e2d epilogue, block-local f32 h: split k over 4 groups of 64, LDS-reduce.
  {
    int r2 = t & 255, g2 = t >> 8;
    float part = 0.0f;
    const float4* wp2 = (const float4*)&e2d_w[(size_t)r2*256 + g2*64];
    const float4* hp4 = (const float4*)&h_s[g2*64];
    #pragma unroll
    for (int k4 = 0; k4 < 16; ++k4) {
      float4 w = wp2[k4];
      float4 h4 = hp4[k4];
      part += w.x*h4.x + w.y*h4.y + w.z*h4.z + w.w*h4.w;
    }
    dot_s[t] = part;
    __syncthreads();
    if (t < 256)
      instr[b*256 + t] = tanhf(e2d_b[t] + dot_s[t] + dot_s[t+256] + dot_s[t+512] + dot_s[t+768]);
  }
}

// ---------------- K2: lin1 -> f16 output, 1 row/thread, grid 1024 (4 blocks/CU for TLP)
__global__ __launch_bounds__(256) void k_lin1(
    const float* __restrict__ instr, const float* __restrict__ w,
    const float* __restrict__ bias, _Float16* __restrict__ f1h)
{
  __shared__ float is[4096];
  int t = threadIdx.x;
  #pragma unroll
  for (int i = 0; i < 16; ++i) is[t + i*256] = instr[t + i*256];
  __syncthreads();
  int r0 = blockIdx.x*256 + t;
  const float* w0 = &w[(size_t)r0*256];
  float acc0[16];
  float bz0 = bias[r0];
  #pragma unroll
  for (int i = 0; i < 16; ++i) acc0[i] = bz0;
  for (int k16 = 0; k16 < 16; ++k16) {
    float4 a[4];
    #pragma unroll
    for (int q = 0; q < 4; ++q)
      a[q] = *(const float4*)&w0[k16*16 + q*4];
    #pragma unroll
    for (int bi = 0; bi < 16; ++bi) {
      #pragma unroll
      for (int q = 0; q < 4; ++q) {
        float4 x = *(const float4*)&is[bi*256 + k16*16 + q*4];
        acc0[bi] += a[q].x*x.x + a[q].y*x.y + a[q].z*x.z + a[q].w*x.w;
      }
    }
  }
  #pragma unroll
  for (int bi = 0; bi < 16; ++bi) {
    float v0 = acc0[bi]; v0 = v0 > 0.0f ? v0 : 0.01f*v0;
    f1h[(size_t)bi*NROW + r0] = (_Float16)v0;
  }
}

// ---------------- K3: f16 MFMA einsum + fused relu->BN->max_r->clip, writes d_out directly.
// Grid: 256 blocks = 16 b x 16 p-tiles(64). Block tile: 256 r x 64 p, K=1024 in chunks of 32.
// mfma_f32_16x16x32_f16: D[m=r][n=p]; C/D: col(n)=lane&15, row(m)=(lane>>4)*4+reg.
__global__ __launch_bounds__(256, 1) void k_einsum_mfma(
    const uint4* __restrict__ f1h4, const float* __restrict__ feat,
    const float* __restrict__ gamma, const float* __restrict__ beta,
    const float* __restrict__ mean, const float* __restrict__ var,
    float* __restrict__ out)
{
  __shared__ unsigned ALDS[256*20];  // [r][40 halves] (32 k + 8 pad) = 20 KB
  __shared__ unsigned BLDS[64*20];   // [p][40 halves]                = 5 KB
  __shared__ float sc_s[256], sh_s[256];
  __shared__ float red[4][64];

  int t = threadIdx.x;
  int b  = blockIdx.x >> 4;
  int P0 = (blockIdx.x & 15) * 64;
  int wr = t >> 6, lane = t & 63;     // wave tile: 64 r x 64 p
  int col = lane & 15, quad = lane >> 4;

  // BN constants
  {
    float s = gamma[t] * rsqrtf(var[t] + 1e-5f);
    sc_s[t] = s;
    sh_s[t] = beta[t] - mean[t]*s;
  }

  f32x4 acc[4][4];
  #pragma unroll
  for (int mt = 0; mt < 4; ++mt)
    #pragma unroll
    for (int nt = 0; nt < 4; ++nt) acc[mt][nt] = (f32x4)0.0f;

  // staging thread roles
  const uint4* arow = f1h4 + ((size_t)b*NROW + (size_t)t*1024)/8;  // f1h row t, uint4 units
  int p_loc = t & 63, kq = t >> 6;   // kq: 4 groups of 8 k-rows
  const float* bbase = feat + ((size_t)b*1024 + kq*8)*1024 + P0 + p_loc;

  // prefetch chunk 0
  uint4 apf[4];
  float bpf[8];
  #pragma unroll
  for (int g = 0; g < 4; ++g) apf[g] = arow[g];
  #pragma unroll
  for (int j = 0; j < 8; ++j) bpf[j] = bbase[(size_t)j*1024];

  for (int kc = 0; kc < 32; ++kc) {
    __syncthreads();   // previous frag reads done; sc_s visible on first iter
    // write staged chunk
    #pragma unroll
    for (int g = 0; g < 4; ++g)
      *(uint4*)&ALDS[t*20 + g*4] = apf[g];
    {
      unsigned u[4];
      #pragma unroll
      for (int c = 0; c < 4; ++c) u[c] = pkh(bpf[2*c], bpf[2*c+1]);
      uint4 w0 = {u[0],u[1],u[2],u[3]};
      *(uint4*)&BLDS[p_loc*20 + kq*4] = w0;
    }
    __syncthreads();
    // prefetch next chunk (overlaps MFMA below)
    if (kc + 1 < 32) {
      #pragma unroll
      for (int g = 0; g < 4; ++g) apf[g] = arow[(kc+1)*4 + g];
      const float* bb = bbase + (size_t)(kc+1)*32*1024;
      #pragma unroll
      for (int j = 0; j < 8; ++j) bpf[j] = bb[(size_t)j*1024];
    }
    // fragments + MFMA
    f16x8 bf[4];
    #pragma unroll
    for (int nt = 0; nt < 4; ++nt) {
      uint4 raw = *(const uint4*)&BLDS[(nt*16 + col)*20 + quad*4];
      bf[nt] = __builtin_bit_cast(f16x8, raw);
    }
    #pragma unroll
    for (int mt = 0; mt < 4; ++mt) {
      uint4 raw = *(const uint4*)&ALDS[(wr*64 + mt*16 + col)*20 + quad*4];
      f16x8 af = __builtin_bit_cast(f16x8, raw);
      #pragma unroll
      for (int nt = 0; nt < 4; ++nt)
        acc[mt][nt] = __builtin_amdgcn_mfma_f32_16x16x32_f16(af, bf[nt], acc[mt][nt], 0, 0, 0);
    }
  }

  // epilogue: relu -> BN -> max over r -> clip -> store
  float pmax[4];
  #pragma unroll
  for (int nt = 0; nt < 4; ++nt) pmax[nt] = -3.4e38f;
  #pragma unroll
  for (int mt = 0; mt < 4; ++mt) {
    int rb = wr*64 + mt*16 + quad*4;
    f32x4 scv = *(const f32x4*)&sc_s[rb];
    f32x4 shv = *(const f32x4*)&sh_s[rb];
    #pragma unroll
    for (int nt = 0; nt < 4; ++nt) {
      f32x4 a = acc[mt][nt];
      #pragma unroll
      for (int reg = 0; reg < 4; ++reg) {
        float v = fmaxf(a[reg], 0.0f)*scv[reg] + shv[reg];
        pmax[nt] = fmaxf(pmax[nt], v);
      }
    }
  }
  #pragma unroll
  for (int nt = 0; nt < 4; ++nt) {
    float m = pmax[nt];
    m = fmaxf(m, __shfl_xor(m, 16));
    m = fmaxf(m, __shfl_xor(m, 32));
    if (lane < 16) red[wr][nt*16 + lane] = m;
  }
  __syncthreads();
  if (t < 64) {
    float v = fmaxf(fmaxf(red[0][t], red[1][t]), fmaxf(red[2][t], red[3][t]));
    out[b*1024 + P0 + t] = fminf(fmaxf(v, 0.0f), 1.0f);
  }
}

extern "C" void kernel_launch(void* const* d_in, const int* in_sizes, int n_in,
                              void* d_out, int out_size, void* d_ws, size_t ws_size,
                              hipStream_t stream)
{
  const float* feature = (const float*)d_in[0];
  // d_in[1] = depth (unused), d_in[4] = only_train_rele (unused)
  const int*   idx     = (const int*)d_in[2];
  const int*   lens    = (const int*)d_in[3];
  const float* emb     = (const float*)d_in[5];
  const float* w_ih    = (const float*)d_in[6];
  const float* w_hh    = (const float*)d_in[7];
  const float* b_ih    = (const float*)d_in[8];
  const float* b_hh    = (const float*)d_in[9];
  const float* e2d_w   = (const float*)d_in[10];
  const float* e2d_b   = (const float*)d_in[11];
  const float* lin1_w  = (const float*)d_in[12];
  const float* lin1_b  = (const float*)d_in[13];
  const float* gamma   = (const float*)d_in[14];
  const float* beta    = (const float*)d_in[15];
  const float* mean    = (const float*)d_in[16];
  const float* var     = (const float*)d_in[17];

  char* ws = (char*)d_ws;
  float*    XG     = (float*)(ws);                 // 640*1024*4  = 2,621,440 B
  float*    instr  = (float*)(ws + 2621440);       // 4096*4      = 16,384 B
  uint4*    W4     = (uint4*)(ws + 2637824);       // 512 KB
  _Float16* f1h    = (_Float16*)(ws + 3162112);    // 16*262144*2 = 8,388,608 B (total ~11.6 MB)

  k_xgates <<<80,   256,  0, stream>>>(idx, emb, w_ih, b_ih, b_hh, XG);
  k_whh4   <<<128,  256,  0, stream>>>(w_hh, W4);
  k_lstm1b <<<16,   1024, 0, stream>>>(XG, W4, lens, e2d_w, e2d_b, instr);
  k_lin1   <<<1024, 256,  0, stream>>>(instr, lin1_w, lin1_b, f1h);
  k_einsum_mfma <<<256, 256, 0, stream>>>((const uint4*)f1h, feature, gamma, beta, mean, var,
                                          (float*)d_out);
}

// Round 4
// 600.999 us; speedup vs baseline: 1.9694x; 1.9694x over previous
//
#include <hip/hip_runtime.h>
#include <hip/hip_fp16.h>
#include <math.h>

// Problem constants
#define NB 16     // batch
#define SQ 40     // seq len
#define HIDN 256  // hidden = E = R
#define CC 1024   // C
#define NROW 262144 // R*C

#define AGENT __HIP_MEMORY_SCOPE_AGENT
#define SENT 0x7E7E7E7Eu   // f16 NaN pattern; real h (tanh*sig, |h|<1) can never produce it

__device__ __forceinline__ float sigf(float x){ return 1.0f/(1.0f+__expf(-x)); }

typedef _Float16 h2v __attribute__((ext_vector_type(2)));
typedef _Float16 f16x8 __attribute__((ext_vector_type(8)));
typedef float    f32x4 __attribute__((ext_vector_type(4)));

__device__ __forceinline__ float fd2(unsigned w, unsigned h, float acc){
  h2v a = __builtin_bit_cast(h2v, w);
  h2v b = __builtin_bit_cast(h2v, h);
#if __has_builtin(__builtin_amdgcn_fdot2)
  return __builtin_amdgcn_fdot2(a, b, acc, false);
#else
  return acc + (float)a.x*(float)b.x + (float)a.y*(float)b.y;
#endif
}

__device__ __forceinline__ unsigned pkh(float lo, float hi){
  return (unsigned)__half_as_ushort(__float2half_rn(lo))
       | ((unsigned)__half_as_ushort(__float2half_rn(hi)) << 16);
}

// ---------------- K0: x-gates precompute: XG[t*16+b][row] = emb[idx[b][t]] . w_ih[row] + b_ih + b_hh
__global__ __launch_bounds__(256) void k_xgates(
    const int* __restrict__ idx, const float* __restrict__ emb,
    const float* __restrict__ w_ih, const float* __restrict__ b_ih,
    const float* __restrict__ b_hh, float* __restrict__ XG)
{
  __shared__ float xs[8*256];
  int t = threadIdx.x;
  int tb0 = blockIdx.x * 8;
  #pragma unroll
  for (int i = 0; i < 8; ++i) {
    int flat = t + i*256;
    int p = flat >> 8, k = flat & 255;
    int tb = tb0 + p;
    int ts = tb >> 4, b = tb & 15;
    int row = idx[b*SQ + ts];
    xs[p*256 + k] = emb[row*256 + k];
  }
  __syncthreads();
  int rows[4];
  float acc[4][8];
  #pragma unroll
  for (int r = 0; r < 4; ++r) {
    rows[r] = t + r*256;
    float bias = b_ih[rows[r]] + b_hh[rows[r]];
    #pragma unroll
    for (int p = 0; p < 8; ++p) acc[r][p] = bias;
  }
  for (int k16 = 0; k16 < 16; ++k16) {
    float4 w[4][4];
    #pragma unroll
    for (int r = 0; r < 4; ++r)
      #pragma unroll
      for (int q = 0; q < 4; ++q)
        w[r][q] = *(const float4*)&w_ih[rows[r]*256 + k16*16 + q*4];
    #pragma unroll
    for (int p = 0; p < 8; ++p) {
      #pragma unroll
      for (int q = 0; q < 4; ++q) {
        float4 x = *(const float4*)&xs[p*256 + k16*16 + q*4];
        #pragma unroll
        for (int r = 0; r < 4; ++r)
          acc[r][p] += w[r][q].x*x.x + w[r][q].y*x.y + w[r][q].z*x.z + w[r][q].w*x.w;
      }
    }
  }
  #pragma unroll
  for (int p = 0; p < 8; ++p)
    #pragma unroll
    for (int r = 0; r < 4; ++r)
      XG[(tb0 + p)*1024 + rows[r]] = acc[r][p];
}

// ---------------- K-whh3: pack w_hh fp32 -> f16-pair, layout for k_lstm2 coalesced reg load.
// u32 flat index: (((half*32 + q)*512 + t)*4 + c); pair = 4q+c; row = (t>>7)*256 + half*128 + (t&127)
__global__ __launch_bounds__(256) void k_whh3(const float* __restrict__ w, unsigned* __restrict__ W3)
{
  int tid = blockIdx.x*256 + threadIdx.x;   // 131072 total
  int c    = tid & 3;
  int tt   = (tid >> 2) & 511;
  int q    = (tid >> 11) & 31;
  int half = tid >> 16;
  int pair = 4*q + c;
  int g = tt >> 7, j = tt & 127;
  int row = g*256 + half*128 + j;
  float2 v = *(const float2*)&w[(size_t)row*256 + 2*pair];
  W3[tid] = pkh(v.x, v.y);
}

// ---------------- K1: LSTM, 2 blocks/batch, register-resident weights, sentinel h-exchange.
// Grid 32 = {b = bid&15, half = bid>>4} (pair lands on same XCD under bid%8 round-robin;
// correctness is placement-independent: agent-scope atomics). Block: 512 thr; thread t owns
// gate row (t>>7)*256 + half*128 + (t&127); its 256 w_hh weights live in 128 packed-f16 VGPRs.
// Per step: own-half fdot2 (h from LDS) -> poll partner's 64 h-pairs (NaN sentinel) ->
// other-half fdot2 -> combine (t<128 holds c,h state) -> publish 64 pairs.
// XG load for step it+1 issued at top of step it (hides L2 latency under the step).
__global__ __launch_bounds__(512) void k_lstm2(
    const float* __restrict__ XG, const uint4* __restrict__ W3,
    const int* __restrict__ lens, const float* __restrict__ e2d_w,
    const float* __restrict__ e2d_b, float* __restrict__ instr,
    unsigned* __restrict__ hcomm)
{
  __shared__ float dot_s[512];
  __shared__ float h_s[128];
  __shared__ float h_e[256];

  int t = threadIdx.x;
  int b    = blockIdx.x & 15;
  int half = blockIdx.x >> 4;
  int len  = lens[b];
  int lane = t & 63;

  // coalesced register weight load: 32 x uint4, lane-interleaved layout
  unsigned wv[128];
  {
    const uint4* wp = W3 + (size_t)half*32*512 + t;
    #pragma unroll
    for (int q = 0; q < 32; ++q) {
      uint4 v = wp[(size_t)q*512];
      wv[4*q+0]=v.x; wv[4*q+1]=v.y; wv[4*q+2]=v.z; wv[4*q+3]=v.w;
    }
  }

  int g = t >> 7, j = t & 127;
  int row = g*256 + half*128 + j;
  float c_reg = 0.0f, h_reg = 0.0f;

  float xg_cur = XG[(0*NB + b)*1024 + row];

  for (int it = 0; it < SQ; ++it) {
    float xg_next = (it+1 < SQ) ? XG[((it+1)*NB + b)*1024 + row] : 0.0f;
    float acc = xg_cur;   // includes b_ih + b_hh
    if (it > 0) {
      // own half of h from LDS (written last iter under barrier)
      unsigned own = pkh(h_s[2*lane], h_s[2*lane + 1]);
      int owni = (int)own;
      const unsigned* oslot = hcomm + ((it-1)*NB + b)*128 + (half ? 0 : 64);
      if (half == 0) {   // own = global pairs 0..63 -> wv[0..63]
        #pragma unroll
        for (int q = 0; q < 64; ++q)
          acc = fd2(wv[q], (unsigned)__builtin_amdgcn_readlane(owni, q), acc);
        unsigned oth;
        do { oth = __hip_atomic_load(oslot + lane, __ATOMIC_RELAXED, AGENT); }
        while (__any((int)(oth == SENT)));
        int othi = (int)oth;
        #pragma unroll
        for (int q = 0; q < 64; ++q)
          acc = fd2(wv[64+q], (unsigned)__builtin_amdgcn_readlane(othi, q), acc);
      } else {           // own = global pairs 64..127 -> wv[64..127]
        #pragma unroll
        for (int q = 0; q < 64; ++q)
          acc = fd2(wv[64+q], (unsigned)__builtin_amdgcn_readlane(owni, q), acc);
        unsigned oth;
        do { oth = __hip_atomic_load(oslot + lane, __ATOMIC_RELAXED, AGENT); }
        while (__any((int)(oth == SENT)));
        int othi = (int)oth;
        #pragma unroll
        for (int q = 0; q < 64; ++q)
          acc = fd2(wv[q], (unsigned)__builtin_amdgcn_readlane(othi, q), acc);
      }
    }
    dot_s[t] = acc;
    __syncthreads();
    if (t < 128) {
      float iv = sigf (dot_s[t]);
      float fv = sigf (dot_s[t + 128]);
      float gv = tanhf(dot_s[t + 256]);
      float ov = sigf (dot_s[t + 384]);
      float cn = fv*c_reg + iv*gv;
      float hn = ov*tanhf(cn);
      if (it < len) { c_reg = cn; h_reg = hn; }
      h_s[t] = h_reg;
    }
    __syncthreads();
    if (t < 64)
      __hip_atomic_store(hcomm + (it*NB + b)*128 + half*64 + t,
                         pkh(h_s[2*t], h_s[2*t+1]), __ATOMIC_RELAXED, AGENT);
    xg_cur = xg_next;
  }

  // e2d epilogue on the half==0 block of each batch
  if (half == 0) {
    const unsigned* slot = hcomm + ((SQ-1)*NB + b)*128;
    if (t < 64) {
      unsigned v0, v1;
      do {
        v0 = __hip_atomic_load(slot + t,      __ATOMIC_RELAXED, AGENT);
        v1 = __hip_atomic_load(slot + 64 + t, __ATOMIC_RELAXED, AGENT);
      } while (__any((int)(v0 == SENT)) || __any((int)(v1 == SENT)));
      h2v lo = __builtin_bit_cast(h2v, v0);
      h2v hi = __builtin_bit_cast(h2v, v1);
      h_e[2*t]       = (float)lo.x;  h_e[2*t + 1]       = (float)lo.y;
      h_e[128 + 2*t] = (float)hi.x;  h_e[128 + 2*t + 1] = (float)hi.y;
    }
    __syncthreads();
    if (t < 256) {
      float acc2 = e2d_b[t];
      const float4* wp2 = (const float4*)&e2d_w[t*256];
      #pragma unroll 8
      for (int k4 = 0; k4 < 64; ++k4) {
        float4 w = wp2[k4];
        float4 h4 = *(const float4*)&h_e[k4*4];
        acc2 += w.x*h4.x + w.y*h4.y + w.z*h4.z + w.w*h4.w;
      }
      instr[b*256 + t] = tanhf(acc2);
    }
  }
}

// ---------------- K2: lin1 -> f16 output, 1 row/thread, grid 1024 (4 blocks/CU for TLP)
__global__ __launch_bounds__(256) void k_lin1(
    const float* __restrict__ instr, const float* __restrict__ w,
    const float* __restrict__ bias, _Float16* __restrict__ f1h)
{
  __shared__ float is[4096];
  int t = threadIdx.x;
  #pragma unroll
  for (int i = 0; i < 16; ++i) is[t + i*256] = instr[t + i*256];
  __syncthreads();
  int r0 = blockIdx.x*256 + t;
  const float* w0 = &w[(size_t)r0*256];
  float acc0[16];
  float bz0 = bias[r0];
  #pragma unroll
  for (int i = 0; i < 16; ++i) acc0[i] = bz0;
  for (int k16 = 0; k16 < 16; ++k16) {
    float4 a[4];
    #pragma unroll
    for (int q = 0; q < 4; ++q)
      a[q] = *(const float4*)&w0[k16*16 + q*4];
    #pragma unroll
    for (int bi = 0; bi < 16; ++bi) {
      #pragma unroll
      for (int q = 0; q < 4; ++q) {
        float4 x = *(const float4*)&is[bi*256 + k16*16 + q*4];
        acc0[bi] += a[q].x*x.x + a[q].y*x.y + a[q].z*x.z + a[q].w*x.w;
      }
    }
  }
  #pragma unroll
  for (int bi = 0; bi < 16; ++bi) {
    float v0 = acc0[bi]; v0 = v0 > 0.0f ? v0 : 0.01f*v0;
    f1h[(size_t)bi*NROW + r0] = (_Float16)v0;
  }
}

// ---------------- K3: f16 MFMA einsum + fused relu->BN->max_r->clip, writes d_out directly.
// Grid: 256 blocks = 16 b x 16 p-tiles(64). Block tile: 256 r x 64 p, K=1024 in chunks of 32.
// mfma_f32_16x16x32_f16: D[m=r][n=p]; C/D: col(n)=lane&15, row(m)=(lane>>4)*4+reg.
__global__ __launch_bounds__(256, 1) void k_einsum_mfma(
    const uint4* __restrict__ f1h4, const float* __restrict__ feat,
    const float* __restrict__ gamma, const float* __restrict__ beta,
    const float* __restrict__ mean, const float* __restrict__ var,
    float* __restrict__ out)
{
  __shared__ unsigned ALDS[256*20];  // [r][40 halves] (32 k + 8 pad) = 20 KB
  __shared__ unsigned BLDS[64*20];   // [p][40 halves]                = 5 KB
  __shared__ float sc_s[256], sh_s[256];
  __shared__ float red[4][64];

  int t = threadIdx.x;
  int b  = blockIdx.x >> 4;
  int P0 = (blockIdx.x & 15) * 64;
  int wr = t >> 6, lane = t & 63;     // wave tile: 64 r x 64 p
  int col = lane & 15, quad = lane >> 4;

  // BN constants
  {
    float s = gamma[t] * rsqrtf(var[t] + 1e-5f);
    sc_s[t] = s;
    sh_s[t] = beta[t] - mean[t]*s;
  }

  f32x4 acc[4][4];
  #pragma unroll
  for (int mt = 0; mt < 4; ++mt)
    #pragma unroll
    for (int nt = 0; nt < 4; ++nt) acc[mt][nt] = (f32x4)0.0f;

  // staging thread roles
  const uint4* arow = f1h4 + ((size_t)b*NROW + (size_t)t*1024)/8;  // f1h row t, uint4 units
  int p_loc = t & 63, kq = t >> 6;   // kq: 4 groups of 8 k-rows
  const float* bbase = feat + ((size_t)b*1024 + kq*8)*1024 + P0 + p_loc;

  // prefetch chunk 0
  uint4 apf[4];
  float bpf[8];
  #pragma unroll
  for (int g = 0; g < 4; ++g) apf[g] = arow[g];
  #pragma unroll
  for (int j = 0; j < 8; ++j) bpf[j] = bbase[(size_t)j*1024];

  for (int kc = 0; kc < 32; ++kc) {
    __syncthreads();   // previous frag reads done; sc_s visible on first iter
    // write staged chunk
    #pragma unroll
    for (int g = 0; g < 4; ++g)
      *(uint4*)&ALDS[t*20 + g*4] = apf[g];
    {
      unsigned u[4];
      #pragma unroll
      for (int c = 0; c < 4; ++c) u[c] = pkh(bpf[2*c], bpf[2*c+1]);
      uint4 w0 = {u[0],u[1],u[2],u[3]};
      *(uint4*)&BLDS[p_loc*20 + kq*4] = w0;
    }
    __syncthreads();
    // prefetch next chunk (overlaps MFMA below)
    if (kc + 1 < 32) {
      #pragma unroll
      for (int g = 0; g < 4; ++g) apf[g] = arow[(kc+1)*4 + g];
      const float* bb = bbase + (size_t)(kc+1)*32*1024;
      #pragma unroll
      for (int j = 0; j < 8; ++j) bpf[j] = bb[(size_t)j*1024];
    }
    // fragments + MFMA
    f16x8 bf[4];
    #pragma unroll
    for (int nt = 0; nt < 4; ++nt) {
      uint4 raw = *(const uint4*)&BLDS[(nt*16 + col)*20 + quad*4];
      bf[nt] = __builtin_bit_cast(f16x8, raw);
    }
    #pragma unroll
    for (int mt = 0; mt < 4; ++mt) {
      uint4 raw = *(const uint4*)&ALDS[(wr*64 + mt*16 + col)*20 + quad*4];
      f16x8 af = __builtin_bit_cast(f16x8, raw);
      #pragma unroll
      for (int nt = 0; nt < 4; ++nt)
        acc[mt][nt] = __builtin_amdgcn_mfma_f32_16x16x32_f16(af, bf[nt], acc[mt][nt], 0, 0, 0);
    }
  }

  // epilogue: relu -> BN -> max over r -> clip -> store
  float pmax[4];
  #pragma unroll
  for (int nt = 0; nt < 4; ++nt) pmax[nt] = -3.4e38f;
  #pragma unroll
  for (int mt = 0; mt < 4; ++mt) {
    int rb = wr*64 + mt*16 + quad*4;
    f32x4 scv = *(const f32x4*)&sc_s[rb];
    f32x4 shv = *(const f32x4*)&sh_s[rb];
    #pragma unroll
    for (int nt = 0; nt < 4; ++nt) {
      f32x4 a = acc[mt][nt];
      #pragma unroll
      for (int reg = 0; reg < 4; ++reg) {
        float v = fmaxf(a[reg], 0.0f)*scv[reg] + shv[reg];
        pmax[nt] = fmaxf(pmax[nt], v);
      }
    }
  }
  #pragma unroll
  for (int nt = 0; nt < 4; ++nt) {
    float m = pmax[nt];
    m = fmaxf(m, __shfl_xor(m, 16));
    m = fmaxf(m, __shfl_xor(m, 32));
    if (lane < 16) red[wr][nt*16 + lane] = m;
  }
  __syncthreads();
  if (t < 64) {
    float v = fmaxf(fmaxf(red[0][t], red[1][t]), fmaxf(red[2][t], red[3][t]));
    out[b*1024 + P0 + t] = fminf(fmaxf(v, 0.0f), 1.0f);
  }
}

extern "C" void kernel_launch(void* const* d_in, const int* in_sizes, int n_in,
                              void* d_out, int out_size, void* d_ws, size_t ws_size,
                              hipStream_t stream)
{
  const float* feature = (const float*)d_in[0];
  // d_in[1] = depth (unused), d_in[4] = only_train_rele (unused)
  const int*   idx     = (const int*)d_in[2];
  const int*   lens    = (const int*)d_in[3];
  const float* emb     = (const float*)d_in[5];
  const float* w_ih    = (const float*)d_in[6];
  const float* w_hh    = (const float*)d_in[7];
  const float* b_ih    = (const float*)d_in[8];
  const float* b_hh    = (const float*)d_in[9];
  const float* e2d_w   = (const float*)d_in[10];
  const float* e2d_b   = (const float*)d_in[11];
  const float* lin1_w  = (const float*)d_in[12];
  const float* lin1_b  = (const float*)d_in[13];
  const float* gamma   = (const float*)d_in[14];
  const float* beta    = (const float*)d_in[15];
  const float* mean    = (const float*)d_in[16];
  const float* var     = (const float*)d_in[17];

  char* ws = (char*)d_ws;
  float*    XG     = (float*)(ws);                 // 640*1024*4  = 2,621,440 B
  float*    instr  = (float*)(ws + 2621440);       // 4096*4      = 16,384 B
  unsigned* W3     = (unsigned*)(ws + 2637824);    // 512 KB
  unsigned* hcomm  = (unsigned*)(ws + 3162112);    // 40*16*128*4 = 327,680 B
  _Float16* f1h    = (_Float16*)(ws + 3489792);    // 16*262144*2 = 8,388,608 B (total ~11.9 MB)

  hipMemsetAsync(hcomm, 0x7E, 327680, stream);     // f16-NaN sentinel in every h slot
  k_xgates <<<80,   256, 0, stream>>>(idx, emb, w_ih, b_ih, b_hh, XG);
  k_whh3   <<<512,  256, 0, stream>>>(w_hh, W3);
  k_lstm2  <<<32,   512, 0, stream>>>(XG, (const uint4*)W3, lens, e2d_w, e2d_b, instr, hcomm);
  k_lin1   <<<1024, 256, 0, stream>>>(instr, lin1_w, lin1_b, f1h);
  k_einsum_mfma <<<256, 256, 0, stream>>>((const uint4*)f1h, feature, gamma, beta, mean, var,
                                          (float*)d_out);
}